// Round 5
// baseline (16633.818 us; speedup 1.0000x reference)
//
#include <hip/hip_runtime.h>
#include <hip/hip_bf16.h>
#include <math.h>

typedef __hip_bfloat16 bf16;

#define Bb 4
#define Tt 2048
#define Cc 2048
#define Hh 32
#define Nn 64
#define BT (Bb*Tt)   // 8192

__device__ __forceinline__ float b2f(bf16 x) { return __bfloat162float(x); }
__device__ __forceinline__ bf16  f2b(float x) { return __float2bfloat16(x); }

// ---------------------------------------------------------------------------
// All inputs are FP32 (reference setup_inputs uses jnp.float32; R2-R4 NaN
// forensics confirmed). Output is FP32. Intermediates stored bf16 in d_ws
// to stay under the workspace budget; all arithmetic in fp32.
// ---------------------------------------------------------------------------

// K1: xm = x + (shift(x) - x) * time_maa_x
__global__ __launch_bounds__(256) void prep_xm_kernel(
    const float* __restrict__ x, const float* __restrict__ maa_x,
    bf16* __restrict__ xm)
{
  int idx = blockIdx.x * 256 + threadIdx.x;   // over B*T*C
  int c  = idx & (Cc - 1);
  int bt = idx >> 11;                          // /Cc
  int t  = bt & (Tt - 1);
  float xv   = x[idx];
  float prev = (t == 0) ? 0.f : x[idx - Cc];
  float xx = prev - xv;
  xm[idx] = f2b(xv + xx * maa_x[c]);
}

// ---------------------------------------------------------------------------
// Tiled GEMM: C[M,N] = A[M,K] (bf16 workspace) * B (fp32 input weights).
// transB: 1 -> B is [N,K] row-major; 0 -> B is [K,N].
// mode: 0 plain->bf16, 1 tanh->bf16, 2 silu->bf16,
//       3 td = bias[n]+acc -> bf16, 4 plain->fp32 (final output)
// ---------------------------------------------------------------------------
#define BM 128
#define BN 128
#define BKk 16

__global__ __launch_bounds__(256) void gemm_kernel(
    const bf16* __restrict__ A, const float* __restrict__ Bm,
    bf16* __restrict__ outB, float* __restrict__ outF,
    const float* __restrict__ bias,
    int M, int N, int K, int transB, int mode)
{
  __shared__ float As[BKk][BM + 1];
  __shared__ float Bs[BKk][BN + 1];
  int tid = threadIdx.x;
  int rowBase = blockIdx.x * BM;
  int colBase = blockIdx.y * BN;
  int tx = tid & 15, ty = tid >> 4;
  float acc[8][8];
  #pragma unroll
  for (int i = 0; i < 8; ++i)
    #pragma unroll
    for (int j = 0; j < 8; ++j) acc[i][j] = 0.f;

  for (int k0 = 0; k0 < K; k0 += BKk) {
    #pragma unroll
    for (int i = 0; i < 8; ++i) {
      int lin = tid + i * 256;
      int r = lin >> 4;
      int kk = lin & 15;
      int gr = rowBase + r, gk = k0 + kk;
      float val = 0.f;
      if (gr < M && gk < K) val = b2f(A[(size_t)gr * K + gk]);
      As[kk][r] = val;
    }
    #pragma unroll
    for (int i = 0; i < 8; ++i) {
      int lin = tid + i * 256;
      float val = 0.f;
      if (transB) {
        int n = lin >> 4, kk = lin & 15;
        int gn = colBase + n, gk = k0 + kk;
        if (gn < N && gk < K) val = Bm[(size_t)gn * K + gk];
        Bs[kk][n] = val;
      } else {
        int kk = lin >> 7, n = lin & 127;
        int gn = colBase + n, gk = k0 + kk;
        if (gn < N && gk < K) val = Bm[(size_t)gk * N + gn];
        Bs[kk][n] = val;
      }
    }
    __syncthreads();
    #pragma unroll
    for (int kk = 0; kk < BKk; ++kk) {
      float a[8], b[8];
      #pragma unroll
      for (int i = 0; i < 8; ++i) a[i] = As[kk][ty * 8 + i];
      #pragma unroll
      for (int j = 0; j < 8; ++j) b[j] = Bs[kk][tx * 8 + j];
      #pragma unroll
      for (int i = 0; i < 8; ++i)
        #pragma unroll
        for (int j = 0; j < 8; ++j)
          acc[i][j] = fmaf(a[i], b[j], acc[i][j]);
    }
    __syncthreads();
  }
  #pragma unroll
  for (int i = 0; i < 8; ++i) {
    int gr = rowBase + ty * 8 + i;
    if (gr >= M) continue;
    #pragma unroll
    for (int j = 0; j < 8; ++j) {
      int gn = colBase + tx * 8 + j;
      if (gn >= N) continue;
      float v = acc[i][j];
      size_t idx = (size_t)gr * N + gn;
      if (mode == 0) {
        outB[idx] = f2b(v);
      } else if (mode == 1) {
        outB[idx] = f2b(tanhf(v));
      } else if (mode == 2) {
        outB[idx] = f2b(v / (1.f + expf(-v)));
      } else if (mode == 3) {
        outB[idx] = f2b(bias[gn] + v);
      } else {
        outF[idx] = v;   // fp32 final output
      }
    }
  }
}

// ---------------------------------------------------------------------------
// K3: fused 5-way token-shift lerp. m[f] = t5row[f*32:(f+1)*32] @ w2[f]
// ---------------------------------------------------------------------------
__global__ __launch_bounds__(256) void lerp5_kernel(
    const float* __restrict__ x, const bf16* __restrict__ t5,
    const float* __restrict__ w2,   // [160, C]
    const float* __restrict__ maa_w, const float* __restrict__ maa_k,
    const float* __restrict__ maa_v, const float* __restrict__ maa_r,
    const float* __restrict__ maa_g,
    bf16* __restrict__ xd, bf16* __restrict__ xk, bf16* __restrict__ xv_,
    bf16* __restrict__ xr, bf16* __restrict__ xg)
{
  __shared__ float t5s[160];
  int bt   = blockIdx.x >> 3;
  int cblk = blockIdx.x & 7;
  int c = cblk * 256 + threadIdx.x;
  if (threadIdx.x < 160) t5s[threadIdx.x] = b2f(t5[(size_t)bt * 160 + threadIdx.x]);
  __syncthreads();
  int t = bt & (Tt - 1);
  size_t idx = (size_t)bt * Cc + c;
  float xv0  = x[idx];
  float prev = (t == 0) ? 0.f : x[idx - Cc];
  float xx = prev - xv0;
  float m[5];
  #pragma unroll
  for (int f = 0; f < 5; ++f) {
    float s = 0.f;
    #pragma unroll
    for (int e = 0; e < 32; ++e)
      s = fmaf(t5s[f * 32 + e], w2[(size_t)(f * 32 + e) * Cc + c], s);
    m[f] = s;
  }
  xd[idx]  = f2b(xv0 + xx * (maa_w[c] + m[0]));
  xk[idx]  = f2b(xv0 + xx * (maa_k[c] + m[1]));
  xv_[idx] = f2b(xv0 + xx * (maa_v[c] + m[2]));
  xr[idx]  = f2b(xv0 + xx * (maa_r[c] + m[3]));
  xg[idx]  = f2b(xv0 + xx * (maa_g[c] + m[4]));
}

// ---------------------------------------------------------------------------
// K5: sequential WKV scan — single-wave, barrier-free, LDS-free.
// One 64-lane wave per (b,h). Lane m owns state column s[n][m] (64 VGPRs).
// out[m] = sum_n r[n]*(u[n]*k[n]*v[m] + s[n][m]); s[n][m] = k[n]*v[m] + w[n]*s
// ---------------------------------------------------------------------------
__global__ __launch_bounds__(64) void wkv_scan_kernel(
    const bf16* __restrict__ r, const bf16* __restrict__ k,
    const bf16* __restrict__ v, const bf16* __restrict__ td,
    const float* __restrict__ u, bf16* __restrict__ out)
{
  int b = blockIdx.x >> 5;     // / Hh
  int h = blockIdx.x & 31;
  int lane = threadIdx.x;      // 0..63 = value index m (and source lane n)
  float uv = u[h * 64 + lane];        // lane n holds u[n]
  float s[64];
  #pragma unroll
  for (int n = 0; n < 64; ++n) s[n] = 0.f;
  size_t base = (size_t)b * Tt * Cc + (size_t)h * 64 + lane;
  for (int t = 0; t < Tt; ++t) {
    float rv = b2f(r[base]);    // lane n holds r[n]
    float kv = b2f(k[base]);
    float vm = b2f(v[base]);    // lane m holds v[m]
    float wv = expf(-expf(b2f(td[base])));
    float acc = 0.f;
    #pragma unroll
    for (int n = 0; n < 64; ++n) {
      float rn = __shfl(rv, n);
      float kn = __shfl(kv, n);
      float wn = __shfl(wv, n);
      float un = __shfl(uv, n);
      float kvv = kn * vm;
      acc = fmaf(rn, fmaf(un, kvv, s[n]), acc);
      s[n] = fmaf(wn, s[n], kvv);
    }
    out[base] = f2b(acc);
    base += Cc;
  }
}

// ---------------------------------------------------------------------------
// K6: GroupNorm over each head (N=64) + affine + gate with g
// ---------------------------------------------------------------------------
__global__ __launch_bounds__(256) void gn_gate_kernel(
    const bf16* __restrict__ wkv, const bf16* __restrict__ g,
    const float* __restrict__ lnw, const float* __restrict__ lnb,
    bf16* __restrict__ out)
{
  int bt = blockIdx.x;
  int wv = threadIdx.x >> 6, lane = threadIdx.x & 63;
  const float EPS = 6.4e-4f;   // 1e-5 * 8^2
  for (int h = wv; h < Hh; h += 4) {
    size_t base = (size_t)bt * Cc + h * 64;
    float x = b2f(wkv[base + lane]);
    float s = x, s2 = x * x;
    #pragma unroll
    for (int off = 1; off < 64; off <<= 1) {
      s  += __shfl_xor(s, off);
      s2 += __shfl_xor(s2, off);
    }
    float mean = s * (1.f / 64.f);
    float var  = s2 * (1.f / 64.f) - mean * mean;
    float inv  = rsqrtf(var + EPS);
    float normed = (x - mean) * inv * lnw[h * 64 + lane] + lnb[h * 64 + lane];
    out[base + lane] = f2b(normed * b2f(g[base + lane]));
  }
}

// ---------------------------------------------------------------------------
// Workspace: 5 x 33.5 MB bf16 [BT,C] + 2.6 MB t5 + 1 MB abuf ~= 171 MB.
// d_out (67 MB fp32) doubles as 33.5 MB bf16 r-scratch mid-pipeline,
// fully overwritten by the final fp32 projection.
// ---------------------------------------------------------------------------
extern "C" void kernel_launch(void* const* d_in, const int* in_sizes, int n_in,
                              void* d_out, int out_size, void* d_ws, size_t ws_size,
                              hipStream_t stream) {
  const float* hidden = (const float*)d_in[0];
  const float* maa_x  = (const float*)d_in[1];
  const float* maa_w  = (const float*)d_in[2];
  const float* maa_k  = (const float*)d_in[3];
  const float* maa_v  = (const float*)d_in[4];
  const float* maa_r  = (const float*)d_in[5];
  const float* maa_g  = (const float*)d_in[6];
  const float* maa_w1 = (const float*)d_in[7];   // [C,160]
  const float* maa_w2 = (const float*)d_in[8];   // [5,32,C] = [160,C]
  const float* tdecay = (const float*)d_in[9];   // [C]
  const float* dw1    = (const float*)d_in[10];  // [C,64]
  const float* dw2    = (const float*)d_in[11];  // [64,C]
  const float* faaaa  = (const float*)d_in[12];  // [H,N]
  const float* w_r    = (const float*)d_in[13];
  const float* w_k    = (const float*)d_in[14];
  const float* w_v    = (const float*)d_in[15];
  const float* w_g    = (const float*)d_in[16];
  const float* w_o    = (const float*)d_in[17];
  const float* lnw    = (const float*)d_in[18];
  const float* lnb    = (const float*)d_in[19];
  float* outF = (float*)d_out;
  bf16* rscratch = (bf16*)d_out;   // first 33.5 MB of the 67 MB fp32 buffer

  char* ws = (char*)d_ws;
  const size_t BUF = (size_t)BT * Cc * sizeof(bf16);   // 33,554,432 B
  bf16* buf0 = (bf16*)(ws + 0 * BUF);
  bf16* buf1 = (bf16*)(ws + 1 * BUF);
  bf16* buf2 = (bf16*)(ws + 2 * BUF);
  bf16* buf3 = (bf16*)(ws + 3 * BUF);
  bf16* buf4 = (bf16*)(ws + 4 * BUF);
  bf16* t5buf = (bf16*)(ws + 5 * BUF);                     // [BT,160]
  bf16* abuf  = (bf16*)(ws + 5 * BUF + 4 * 1024 * 1024);   // [BT,64]

  dim3 blk(256);

  // 1. xm -> buf0
  prep_xm_kernel<<<dim3(BT * Cc / 256), blk, 0, stream>>>(hidden, maa_x, buf0);

  // 2. t5 = tanh(xm @ maa_w1): M=8192,N=160,K=2048. buf0 dead after.
  gemm_kernel<<<dim3(64, 2), blk, 0, stream>>>(buf0, maa_w1, t5buf, nullptr, nullptr,
                                               BT, 160, Cc, 0, 1);

  // 3. fused lerp -> xd(1) xk(2) xv(3) xr(4) xg(0)
  lerp5_kernel<<<dim3(BT * 8), blk, 0, stream>>>(hidden, t5buf, maa_w2,
      maa_w, maa_k, maa_v, maa_r, maa_g, buf1, buf2, buf3, buf4, buf0);

  // 4. decay: a = tanh(xd @ dw1) [8192,64]; td = tdecay + a @ dw2 -> buf1
  gemm_kernel<<<dim3(64, 1), blk, 0, stream>>>(buf1, dw1, abuf, nullptr, nullptr,
                                               BT, 64, Cc, 0, 1);
  gemm_kernel<<<dim3(64, 16), blk, 0, stream>>>(abuf, dw2, buf1, nullptr, tdecay,
                                                BT, Cc, 64, 0, 3);

  // 5. projections (B transposed): r->rscratch, k->buf4, v->buf2, g(silu)->buf3
  gemm_kernel<<<dim3(64, 16), blk, 0, stream>>>(buf4, w_r, rscratch, nullptr, nullptr,
                                                BT, Cc, Cc, 1, 0);
  gemm_kernel<<<dim3(64, 16), blk, 0, stream>>>(buf2, w_k, buf4, nullptr, nullptr,
                                                BT, Cc, Cc, 1, 0);
  gemm_kernel<<<dim3(64, 16), blk, 0, stream>>>(buf3, w_v, buf2, nullptr, nullptr,
                                                BT, Cc, Cc, 1, 0);
  gemm_kernel<<<dim3(64, 16), blk, 0, stream>>>(buf0, w_g, buf3, nullptr, nullptr,
                                                BT, Cc, Cc, 1, 2);

  // 6. WKV scan: r=rscratch, k=buf4, v=buf2, td=buf1 -> wkv -> buf0
  wkv_scan_kernel<<<dim3(Bb * Hh), dim3(64), 0, stream>>>(rscratch, buf4, buf2, buf1,
                                                          faaaa, buf0);

  // 7. GroupNorm + gate -> buf4
  gn_gate_kernel<<<dim3(BT), blk, 0, stream>>>(buf0, buf3, lnw, lnb, buf4);

  // 8. final projection -> d_out as FP32 (fully overwrites rscratch region)
  gemm_kernel<<<dim3(64, 16), blk, 0, stream>>>(buf4, w_o, nullptr, outF, nullptr,
                                                BT, Cc, Cc, 1, 4);
}

// Round 6
// 4813.885 us; speedup vs baseline: 3.4554x; 3.4554x over previous
//
#include <hip/hip_runtime.h>
#include <hip/hip_bf16.h>
#include <math.h>

typedef __hip_bfloat16 bf16;
typedef __attribute__((ext_vector_type(8))) short short8;   // 8 bf16 = 4 VGPRs
typedef __attribute__((ext_vector_type(4))) float f32x4;

#define Bb 4
#define Tt 2048
#define Cc 2048
#define Hh 32
#define Nn 64
#define BT (Bb*Tt)   // 8192

__device__ __forceinline__ float b2f(bf16 x) { return __bfloat162float(x); }
__device__ __forceinline__ bf16  f2b(float x) { return __float2bfloat16(x); }

// ---------------------------------------------------------------------------
// K0: fp32 -> bf16 weight conversion (for MFMA GEMMs)
// ---------------------------------------------------------------------------
__global__ __launch_bounds__(256) void cvt_kernel(
    const float* __restrict__ in, bf16* __restrict__ out)
{
  int i = blockIdx.x * 256 + threadIdx.x;
  out[i] = f2b(in[i]);
}

// ---------------------------------------------------------------------------
// K1: xm = x + (shift(x) - x) * time_maa_x
// ---------------------------------------------------------------------------
__global__ __launch_bounds__(256) void prep_xm_kernel(
    const float* __restrict__ x, const float* __restrict__ maa_x,
    bf16* __restrict__ xm)
{
  int idx = blockIdx.x * 256 + threadIdx.x;
  int c  = idx & (Cc - 1);
  int bt = idx >> 11;
  int t  = bt & (Tt - 1);
  float xv   = x[idx];
  float prev = (t == 0) ? 0.f : x[idx - Cc];
  xm[idx] = f2b(xv + (prev - xv) * maa_x[c]);
}

// ---------------------------------------------------------------------------
// MFMA GEMM: C[8192,2048] = A[8192,2048](bf16) * B^T, B[2048,2048](bf16,[N,K])
// 128x128 block tile, 4 waves in 2x2, each wave 64x64 via 4x4 16x16x32 MFMAs.
// mode: 0 plain->bf16, 2 silu->bf16, 4 plain->fp32
// Fragment maps (HW-verified, guide §3): A/B operand [idx=lane&15][k=quad*8+j];
// C/D col=lane&15, row=quad*4+reg.
// ---------------------------------------------------------------------------
#define LDA 40   // padded LDS row (bf16 elems): 20 dwords -> ~2-way conflicts

__global__ __launch_bounds__(256) void mfma_gemm_kernel(
    const bf16* __restrict__ A, const bf16* __restrict__ B,
    bf16* __restrict__ outB, float* __restrict__ outF, int mode)
{
  __shared__ bf16 As[128 * LDA];
  __shared__ bf16 Bs[128 * LDA];
  int tid  = threadIdx.x;
  int lane = tid & 63, wid = tid >> 6;
  int wm = wid & 1, wn = wid >> 1;
  int quad = lane >> 4, l16 = lane & 15;
  size_t rowBase = (size_t)blockIdx.x * 128;
  size_t colBase = (size_t)blockIdx.y * 128;

  f32x4 acc[4][4];
  #pragma unroll
  for (int i = 0; i < 4; ++i)
    #pragma unroll
    for (int j = 0; j < 4; ++j)
      acc[i][j] = (f32x4){0.f, 0.f, 0.f, 0.f};

  for (int k0 = 0; k0 < 2048; k0 += 32) {
    // stage 128x32 A and B tiles; 16B vector loads, 2 passes x 256 threads
    #pragma unroll
    for (int pass = 0; pass < 2; ++pass) {
      int chunk = tid + pass * 256;           // 0..511
      int row = chunk >> 2, kc = (chunk & 3) * 8;
      short8 av = *(const short8*)(A + (rowBase + row) * 2048 + k0 + kc);
      short8 bv = *(const short8*)(B + (colBase + row) * 2048 + k0 + kc);
      *(short8*)(As + row * LDA + kc) = av;
      *(short8*)(Bs + row * LDA + kc) = bv;
    }
    __syncthreads();
    short8 af[4], bf[4];
    #pragma unroll
    for (int i = 0; i < 4; ++i) {
      af[i] = *(const short8*)(As + (wm * 64 + i * 16 + l16) * LDA + quad * 8);
      bf[i] = *(const short8*)(Bs + (wn * 64 + i * 16 + l16) * LDA + quad * 8);
    }
    #pragma unroll
    for (int i = 0; i < 4; ++i)
      #pragma unroll
      for (int j = 0; j < 4; ++j)
        acc[i][j] = __builtin_amdgcn_mfma_f32_16x16x32_bf16(af[i], bf[j], acc[i][j], 0, 0, 0);
    __syncthreads();
  }

  #pragma unroll
  for (int i = 0; i < 4; ++i) {
    #pragma unroll
    for (int j = 0; j < 4; ++j) {
      int gc = colBase + wn * 64 + j * 16 + l16;
      #pragma unroll
      for (int reg = 0; reg < 4; ++reg) {
        int gr = rowBase + wm * 64 + i * 16 + quad * 4 + reg;
        float v = acc[i][j][reg];
        size_t idx = (size_t)gr * 2048 + gc;
        if (mode == 0)      outB[idx] = f2b(v);
        else if (mode == 2) outB[idx] = f2b(v / (1.f + expf(-v)));
        else                outF[idx] = v;
      }
    }
  }
}

// ---------------------------------------------------------------------------
// VALU tiled GEMM for small/skinny shapes. A bf16, B fp32.
// transB: 1 -> B[N,K]; 0 -> B[K,N].
// mode: 1 tanh->bf16, 3 td = bias[n]+acc -> bf16
// ---------------------------------------------------------------------------
#define BM 128
#define BN 128
#define BKk 16

__global__ __launch_bounds__(256) void gemm_kernel(
    const bf16* __restrict__ A, const float* __restrict__ Bm,
    bf16* __restrict__ outB,
    const float* __restrict__ bias,
    int M, int N, int K, int transB, int mode)
{
  __shared__ float As[BKk][BM + 1];
  __shared__ float Bs[BKk][BN + 1];
  int tid = threadIdx.x;
  int rowBase = blockIdx.x * BM;
  int colBase = blockIdx.y * BN;
  int tx = tid & 15, ty = tid >> 4;
  float acc[8][8];
  #pragma unroll
  for (int i = 0; i < 8; ++i)
    #pragma unroll
    for (int j = 0; j < 8; ++j) acc[i][j] = 0.f;

  for (int k0 = 0; k0 < K; k0 += BKk) {
    #pragma unroll
    for (int i = 0; i < 8; ++i) {
      int lin = tid + i * 256;
      int r = lin >> 4, kk = lin & 15;
      int gr = rowBase + r, gk = k0 + kk;
      float val = 0.f;
      if (gr < M && gk < K) val = b2f(A[(size_t)gr * K + gk]);
      As[kk][r] = val;
    }
    #pragma unroll
    for (int i = 0; i < 8; ++i) {
      int lin = tid + i * 256;
      float val = 0.f;
      if (transB) {
        int n = lin >> 4, kk = lin & 15;
        int gn = colBase + n, gk = k0 + kk;
        if (gn < N && gk < K) val = Bm[(size_t)gn * K + gk];
        Bs[kk][n] = val;
      } else {
        int kk = lin >> 7, n = lin & 127;
        int gn = colBase + n, gk = k0 + kk;
        if (gn < N && gk < K) val = Bm[(size_t)gk * N + gn];
        Bs[kk][n] = val;
      }
    }
    __syncthreads();
    #pragma unroll
    for (int kk = 0; kk < BKk; ++kk) {
      float a[8], b[8];
      #pragma unroll
      for (int i = 0; i < 8; ++i) a[i] = As[kk][ty * 8 + i];
      #pragma unroll
      for (int j = 0; j < 8; ++j) b[j] = Bs[kk][tx * 8 + j];
      #pragma unroll
      for (int i = 0; i < 8; ++i)
        #pragma unroll
        for (int j = 0; j < 8; ++j)
          acc[i][j] = fmaf(a[i], b[j], acc[i][j]);
    }
    __syncthreads();
  }
  #pragma unroll
  for (int i = 0; i < 8; ++i) {
    int gr = rowBase + ty * 8 + i;
    if (gr >= M) continue;
    #pragma unroll
    for (int j = 0; j < 8; ++j) {
      int gn = colBase + tx * 8 + j;
      if (gn >= N) continue;
      float v = acc[i][j];
      size_t idx = (size_t)gr * N + gn;
      if (mode == 1)      outB[idx] = f2b(tanhf(v));
      else                outB[idx] = f2b(bias[gn] + v);   // mode 3
    }
  }
}

// ---------------------------------------------------------------------------
// K3: fused 5-way token-shift lerp. m[f] = t5row[f*32:(f+1)*32] @ w2[f]
// ---------------------------------------------------------------------------
__global__ __launch_bounds__(256) void lerp5_kernel(
    const float* __restrict__ x, const bf16* __restrict__ t5,
    const float* __restrict__ w2,   // [160, C]
    const float* __restrict__ maa_w, const float* __restrict__ maa_k,
    const float* __restrict__ maa_v, const float* __restrict__ maa_r,
    const float* __restrict__ maa_g,
    bf16* __restrict__ xd, bf16* __restrict__ xk, bf16* __restrict__ xv_,
    bf16* __restrict__ xr, bf16* __restrict__ xg)
{
  __shared__ float t5s[160];
  int bt   = blockIdx.x >> 3;
  int cblk = blockIdx.x & 7;
  int c = cblk * 256 + threadIdx.x;
  if (threadIdx.x < 160) t5s[threadIdx.x] = b2f(t5[(size_t)bt * 160 + threadIdx.x]);
  __syncthreads();
  int t = bt & (Tt - 1);
  size_t idx = (size_t)bt * Cc + c;
  float xv0  = x[idx];
  float prev = (t == 0) ? 0.f : x[idx - Cc];
  float xx = prev - xv0;
  float m[5];
  #pragma unroll
  for (int f = 0; f < 5; ++f) {
    float s = 0.f;
    #pragma unroll
    for (int e = 0; e < 32; ++e)
      s = fmaf(t5s[f * 32 + e], w2[(size_t)(f * 32 + e) * Cc + c], s);
    m[f] = s;
  }
  xd[idx]  = f2b(xv0 + xx * (maa_w[c] + m[0]));
  xk[idx]  = f2b(xv0 + xx * (maa_k[c] + m[1]));
  xv_[idx] = f2b(xv0 + xx * (maa_v[c] + m[2]));
  xr[idx]  = f2b(xv0 + xx * (maa_r[c] + m[3]));
  xg[idx]  = f2b(xv0 + xx * (maa_g[c] + m[4]));
}

// ---------------------------------------------------------------------------
// K5: WKV scan, 256 threads per (b,h). Thread (chunk=tid>>6, m=tid&63) owns
// state s[chunk*16 .. +16)[m] in regs. rkw broadcast via LDS float4 (b128,
// wave-uniform address each iter -> broadcast, conflict-free). u in regs.
// out[m] = sum_n r[n]*(u[n]*k[n]*v[m] + s[n][m]); s = k[n]*v[m] + w[n]*s
// ---------------------------------------------------------------------------
__global__ __launch_bounds__(256) void wkv_scan_kernel(
    const bf16* __restrict__ r, const bf16* __restrict__ k,
    const bf16* __restrict__ v, const bf16* __restrict__ td,
    const float* __restrict__ u, bf16* __restrict__ out)
{
  int b = blockIdx.x >> 5;
  int h = blockIdx.x & 31;
  int tid = threadIdx.x;
  int m = tid & 63, chunk = tid >> 6;
  __shared__ float4 rkw[64];
  __shared__ float vs[64];
  __shared__ float red[256];
  float ureg[16], s[16];
  #pragma unroll
  for (int i = 0; i < 16; ++i) {
    s[i] = 0.f;
    ureg[i] = u[h * 64 + chunk * 16 + i];
  }
  size_t base = (size_t)b * Tt * Cc + (size_t)h * 64;
  for (int t = 0; t < Tt; ++t, base += Cc) {
    if (tid < 64) {
      float rv = b2f(r[base + tid]);
      float kv = b2f(k[base + tid]);
      float wv = expf(-expf(b2f(td[base + tid])));
      rkw[tid] = make_float4(rv, kv, wv, 0.f);
      vs[tid]  = b2f(v[base + tid]);
    }
    __syncthreads();
    float vm = vs[m];
    float acc = 0.f;
    #pragma unroll
    for (int i = 0; i < 16; ++i) {
      float4 q = rkw[chunk * 16 + i];
      float kv = q.y * vm;
      acc = fmaf(q.x, fmaf(ureg[i], kv, s[i]), acc);
      s[i] = fmaf(q.z, s[i], kv);
    }
    red[tid] = acc;
    __syncthreads();
    if (tid < 64)
      out[base + tid] = f2b(red[tid] + red[tid + 64] + red[tid + 128] + red[tid + 192]);
  }
}

// ---------------------------------------------------------------------------
// K6: GroupNorm over each head (N=64) + affine + gate with g
// ---------------------------------------------------------------------------
__global__ __launch_bounds__(256) void gn_gate_kernel(
    const bf16* __restrict__ wkv, const bf16* __restrict__ g,
    const float* __restrict__ lnw, const float* __restrict__ lnb,
    bf16* __restrict__ out)
{
  int bt = blockIdx.x;
  int wv = threadIdx.x >> 6, lane = threadIdx.x & 63;
  const float EPS = 6.4e-4f;   // 1e-5 * 8^2
  for (int h = wv; h < Hh; h += 4) {
    size_t base = (size_t)bt * Cc + h * 64;
    float x = b2f(wkv[base + lane]);
    float s = x, s2 = x * x;
    #pragma unroll
    for (int off = 1; off < 64; off <<= 1) {
      s  += __shfl_xor(s, off);
      s2 += __shfl_xor(s2, off);
    }
    float mean = s * (1.f / 64.f);
    float var  = s2 * (1.f / 64.f) - mean * mean;
    float inv  = rsqrtf(var + EPS);
    float normed = (x - mean) * inv * lnw[h * 64 + lane] + lnb[h * 64 + lane];
    out[base + lane] = f2b(normed * b2f(g[base + lane]));
  }
}

// ---------------------------------------------------------------------------
// Workspace: 5 x 33.55 MB bf16 [BT,C] + 4 MB t5 + 4 MB abuf + 5 x 8.39 MB
// bf16 weights ~= 218 MB. d_out (67 MB fp32) doubles as bf16 r-scratch.
// ---------------------------------------------------------------------------
extern "C" void kernel_launch(void* const* d_in, const int* in_sizes, int n_in,
                              void* d_out, int out_size, void* d_ws, size_t ws_size,
                              hipStream_t stream) {
  const float* hidden = (const float*)d_in[0];
  const float* maa_x  = (const float*)d_in[1];
  const float* maa_w  = (const float*)d_in[2];
  const float* maa_k  = (const float*)d_in[3];
  const float* maa_v  = (const float*)d_in[4];
  const float* maa_r  = (const float*)d_in[5];
  const float* maa_g  = (const float*)d_in[6];
  const float* maa_w1 = (const float*)d_in[7];   // [C,160]
  const float* maa_w2 = (const float*)d_in[8];   // [160,C]
  const float* tdecay = (const float*)d_in[9];   // [C]
  const float* dw1    = (const float*)d_in[10];  // [C,64]
  const float* dw2    = (const float*)d_in[11];  // [64,C]
  const float* faaaa  = (const float*)d_in[12];  // [H,N]
  const float* w_r    = (const float*)d_in[13];
  const float* w_k    = (const float*)d_in[14];
  const float* w_v    = (const float*)d_in[15];
  const float* w_g    = (const float*)d_in[16];
  const float* w_o    = (const float*)d_in[17];
  const float* lnw    = (const float*)d_in[18];
  const float* lnb    = (const float*)d_in[19];
  float* outF = (float*)d_out;
  bf16* rscratch = (bf16*)d_out;

  char* ws = (char*)d_ws;
  const size_t BUF  = (size_t)BT * Cc * sizeof(bf16);   // 33,554,432 B
  const size_t WBUF = (size_t)Cc * Cc * sizeof(bf16);   //  8,388,608 B
  bf16* buf0 = (bf16*)(ws + 0 * BUF);
  bf16* buf1 = (bf16*)(ws + 1 * BUF);
  bf16* buf2 = (bf16*)(ws + 2 * BUF);
  bf16* buf3 = (bf16*)(ws + 3 * BUF);
  bf16* buf4 = (bf16*)(ws + 4 * BUF);
  bf16* t5buf = (bf16*)(ws + 5 * BUF);
  bf16* abuf  = (bf16*)(ws + 5 * BUF + 4 * 1024 * 1024);
  char* wbase = ws + 5 * BUF + 8 * 1024 * 1024;
  bf16* wrb = (bf16*)(wbase + 0 * WBUF);
  bf16* wkb = (bf16*)(wbase + 1 * WBUF);
  bf16* wvb = (bf16*)(wbase + 2 * WBUF);
  bf16* wgb = (bf16*)(wbase + 3 * WBUF);
  bf16* wob = (bf16*)(wbase + 4 * WBUF);

  dim3 blk(256);
  const int CVT_G = Cc * Cc / 256;   // 16384

  // 0. weight conversions (independent of data pipeline)
  cvt_kernel<<<dim3(CVT_G), blk, 0, stream>>>(w_r, wrb);
  cvt_kernel<<<dim3(CVT_G), blk, 0, stream>>>(w_k, wkb);
  cvt_kernel<<<dim3(CVT_G), blk, 0, stream>>>(w_v, wvb);
  cvt_kernel<<<dim3(CVT_G), blk, 0, stream>>>(w_g, wgb);
  cvt_kernel<<<dim3(CVT_G), blk, 0, stream>>>(w_o, wob);

  // 1. xm -> buf0
  prep_xm_kernel<<<dim3(BT * Cc / 256), blk, 0, stream>>>(hidden, maa_x, buf0);

  // 2. t5 = tanh(xm @ maa_w1): M=8192,N=160,K=2048
  gemm_kernel<<<dim3(64, 2), blk, 0, stream>>>(buf0, maa_w1, t5buf, nullptr,
                                               BT, 160, Cc, 0, 1);

  // 3. fused lerp -> xd(1) xk(2) xv(3) xr(4) xg(0)
  lerp5_kernel<<<dim3(BT * 8), blk, 0, stream>>>(hidden, t5buf, maa_w2,
      maa_w, maa_k, maa_v, maa_r, maa_g, buf1, buf2, buf3, buf4, buf0);

  // 4. decay: a = tanh(xd @ dw1) [8192,64]; td = tdecay + a @ dw2 -> buf1
  gemm_kernel<<<dim3(64, 1), blk, 0, stream>>>(buf1, dw1, abuf, nullptr,
                                               BT, 64, Cc, 0, 1);
  gemm_kernel<<<dim3(64, 16), blk, 0, stream>>>(abuf, dw2, buf1, tdecay,
                                                BT, Cc, 64, 0, 3);

  // 5. projections (MFMA): r->rscratch, k->buf4, v->buf2, g(silu)->buf3
  mfma_gemm_kernel<<<dim3(64, 16), blk, 0, stream>>>(buf4, wrb, rscratch, nullptr, 0);
  mfma_gemm_kernel<<<dim3(64, 16), blk, 0, stream>>>(buf2, wkb, buf4, nullptr, 0);
  mfma_gemm_kernel<<<dim3(64, 16), blk, 0, stream>>>(buf3, wvb, buf2, nullptr, 0);
  mfma_gemm_kernel<<<dim3(64, 16), blk, 0, stream>>>(buf0, wgb, buf3, nullptr, 2);

  // 6. WKV scan: r=rscratch, k=buf4, v=buf2, td=buf1 -> buf0
  wkv_scan_kernel<<<dim3(Bb * Hh), blk, 0, stream>>>(rscratch, buf4, buf2, buf1,
                                                     faaaa, buf0);

  // 7. GroupNorm + gate -> buf4
  gn_gate_kernel<<<dim3(BT), blk, 0, stream>>>(buf0, buf3, lnw, lnb, buf4);

  // 8. final projection (MFMA) -> d_out fp32
  mfma_gemm_kernel<<<dim3(64, 16), blk, 0, stream>>>(buf4, wob, nullptr, outF, 4);
}